// Round 8
// baseline (74.836 us; speedup 1.0000x reference)
//
#include <hip/hip_runtime.h>
#include <hip/hip_cooperative_groups.h>
#include <math.h>

namespace cg = cooperative_groups;

#define NDET 10647
#define NB 4
#define NCLS 80
#define CAP 160   // per-(image,class) bucket capacity; expected ~66±8, 160 ≈ 11 sigma

// numerically-stable sigmoid, mirrors jax.nn.sigmoid's f32 behavior
__device__ __forceinline__ float sigmoidf_ref(float x) {
    if (x >= 0.f) {
        return 1.f / (1.f + expf(-x));
    } else {
        float e = expf(x);
        return e / (1.f + e);
    }
}

// Thread-per-cell decode: for fixed channel j, consecutive (h*S+w) cells are
// contiguous in memory -> every load in the j-loop is a fully coalesced
// wave read. 85 independent loads per thread, no LDS. Class argmax on RAW
// logits (sigmoid monotonic; first-max strict-> tie rule preserved by
// in-order 4-chain merge).
template <int S>
__device__ __forceinline__ void decode_cell(
    const float* __restrict__ feat, int b, int a, int cell, int off, float sx,
    float anchw, float anchh, float* __restrict__ det, float* __restrict__ keep,
    int* __restrict__ counts, float4* __restrict__ bbox,
    float* __restrict__ bconf, int* __restrict__ bidx)
{
    const int SS = S * S;
    const int h = cell / S;
    const int w = cell - h * S;
    const float* p = feat + ((size_t)(b * 255 + a * 85)) * SS + cell;

    float t0 = p[0 * SS];
    float t1 = p[1 * SS];
    float t2 = p[2 * SS];
    float t3 = p[3 * SS];
    float t4 = p[4 * SS];

    // load all 80 class logits into registers (compile-time indices only)
    float v[80];
#pragma unroll
    for (int j = 0; j < 80; ++j) v[j] = p[(size_t)(5 + j) * SS];

    // 4 independent chains over contiguous ranges, merged in index order
    float m0 = v[0], m1 = v[20], m2 = v[40], m3 = v[60];
    int i0 = 0, i1 = 20, i2 = 40, i3 = 60;
#pragma unroll
    for (int j = 1; j < 20; ++j) {
        if (v[j]      > m0) { m0 = v[j];      i0 = j; }
        if (v[20 + j] > m1) { m1 = v[20 + j]; i1 = 20 + j; }
        if (v[40 + j] > m2) { m2 = v[40 + j]; i2 = 40 + j; }
        if (v[60 + j] > m3) { m3 = v[60 + j]; i3 = 60 + j; }
    }
    float best = m0; int cls = i0;
    if (m1 > best) { best = m1; cls = i1; }
    if (m2 > best) { best = m2; cls = i2; }
    if (m3 > best) { best = m3; cls = i3; }

    float x  = (sigmoidf_ref(t0) + (float)w) * sx;
    float y  = (sigmoidf_ref(t1) + (float)h) * sx;
    float bw = expf(t2) * anchw * sx;
    float bh = expf(t3) * anchh * sx;
    float conf = sigmoidf_ref(t4);

    float b0 = x - bw * 0.5f;
    float b1 = x + bw * 0.5f;
    float b2 = y - bh * 0.5f;
    float b3 = y + bh * 0.5f;

    const int n = off + (w * S + h) * 3 + a;
    // det rows are 6 floats = 24B -> always 8B aligned: three float2 stores
    float2* o = reinterpret_cast<float2*>(det + ((size_t)b * NDET + n) * 6);
    o[0] = make_float2(b0, b1);
    o[1] = make_float2(b2, b3);
    o[2] = make_float2(conf, (float)cls);

    if (conf > 0.5f) {
        int bk = b * NCLS + cls;
        int pos = atomicAdd(&counts[bk], 1);
        if (pos < CAP) {
            int slot = bk * CAP + pos;
            bbox[slot]  = make_float4(b0, b1, b2, b3);
            bconf[slot] = conf;
            bidx[slot]  = n;
        }
    } else {
        keep[(size_t)b * NDET + n] = 0.f;
    }
}

// Fused decode + grid-sync + bucketed NMS. 320 blocks x 256 threads,
// cooperative launch (all blocks co-resident: ~2 blocks/CU).
// Decode phase: blocks 0..179 = (cx 0..14, a 0..2, b 0..3), exact R5 mapping.
// NMS phase: block bx = bucket bx (b*NCLS+cls).
__global__ __launch_bounds__(256) void fused_kernel(
    const float* __restrict__ f0, const float* __restrict__ f1,
    const float* __restrict__ f2, float* __restrict__ det,
    float* __restrict__ keep, int* __restrict__ counts,
    float4* __restrict__ bbox, float* __restrict__ bconf, int* __restrict__ bidx)
{
    const int bx = blockIdx.x;
    const int tid = threadIdx.x;

    // ---------------- decode phase ----------------
    if (bx < 180) {
        const int cx = bx % 15;
        const int ab = bx / 15;
        const int a = ab % 3;
        const int b = ab / 3;

        if (cx < 11) {
            int cell = cx * 256 + tid;
            if (cell < 52 * 52) {
                const float aw[3] = {10.f, 16.f, 33.f}, ah[3] = {13.f, 30.f, 23.f};
                decode_cell<52>(f0, b, a, cell, 0, 8.f, aw[a], ah[a],
                                det, keep, counts, bbox, bconf, bidx);
            }
        } else if (cx < 14) {
            int cell = (cx - 11) * 256 + tid;
            if (cell < 26 * 26) {
                const float aw[3] = {30.f, 62.f, 59.f}, ah[3] = {61.f, 45.f, 119.f};
                decode_cell<26>(f1, b, a, cell, 8112, 16.f, aw[a], ah[a],
                                det, keep, counts, bbox, bconf, bidx);
            }
        } else {
            int cell = tid;
            if (cell < 13 * 13) {
                const float aw[3] = {116.f, 156.f, 373.f}, ah[3] = {90.f, 198.f, 326.f};
                decode_cell<13>(f2, b, a, cell, 10140, 32.f, aw[a], ah[a],
                                det, keep, counts, bbox, bconf, bidx);
            }
        }
    }

    cg::this_grid().sync();

    // ---------------- NMS phase ----------------
    const int bk = bx;                  // b*NCLS + cls
    const int b = bk / NCLS;
    int cnt = counts[bk];
    if (cnt > CAP) cnt = CAP;

    __shared__ float4 sb[CAP];
    __shared__ float  sc[CAP];
    __shared__ int    si[CAP];
    const int t = tid;
    if (t < cnt) {
        sb[t] = bbox[bk * CAP + t];
        sc[t] = bconf[bk * CAP + t];
        si[t] = bidx[bk * CAP + t];
    }
    __syncthreads();
    if (t >= cnt) return;

    float4 me = sb[t];
    float ci = sc[t];
    // replicate reference exactly: area uses (b2-b0) x (b3-b1)
    float ai = fmaxf(me.z - me.x + 1.f, 0.f) * fmaxf(me.w - me.y + 1.f, 0.f);
    float kv = 0.f;
    for (int j = 0; j < cnt; ++j) {
        float cj = sc[j];
        float4 c = sb[j];
        float xmin = fmaxf(me.x, c.x);
        float ymin = fmaxf(me.y, c.y);
        float xmax = fminf(me.z, c.z);
        float ymax = fminf(me.w, c.w);
        float inter = fmaxf(xmax - xmin + 1.f, 0.f) * fmaxf(ymax - ymin + 1.f, 0.f);
        float aj = fmaxf(c.z - c.x + 1.f, 0.f) * fmaxf(c.w - c.y + 1.f, 0.f);
        float iou = inter / (ai + aj - inter);
        // NaN (0/0) compares false, same as numpy
        if (cj > ci && iou > 0.4f) kv = 1.f;
    }
    keep[(size_t)b * NDET + si[t]] = kv;
}

extern "C" void kernel_launch(void* const* d_in, const int* in_sizes, int n_in,
                              void* d_out, int out_size, void* d_ws, size_t ws_size,
                              hipStream_t stream) {
    const float* f0 = (const float*)d_in[0];
    const float* f1 = (const float*)d_in[1];
    const float* f2 = (const float*)d_in[2];
    float* det  = (float*)d_out;                       // (B, 10647, 6)
    float* keep = det + (size_t)NB * NDET * 6;         // (B, 10647) as 0/1 floats

    // workspace layout
    char* ws = (char*)d_ws;
    int* counts = (int*)ws;                             ws += NB * NCLS * sizeof(int);
    ws = (char*)(((uintptr_t)ws + 15) & ~(uintptr_t)15);
    float4* bbox = (float4*)ws;                         ws += (size_t)NB * NCLS * CAP * sizeof(float4);
    float* bconf = (float*)ws;                          ws += (size_t)NB * NCLS * CAP * sizeof(float);
    int*   bidx  = (int*)ws;

    hipMemsetAsync(counts, 0, NB * NCLS * sizeof(int), stream);

    void* args[] = { (void*)&f0, (void*)&f1, (void*)&f2, (void*)&det,
                     (void*)&keep, (void*)&counts, (void*)&bbox,
                     (void*)&bconf, (void*)&bidx };
    hipLaunchCooperativeKernel((const void*)fused_kernel, dim3(320), dim3(256),
                               args, 0, stream);
}

// Round 9
// 33.786 us; speedup vs baseline: 2.2150x; 2.2150x over previous
//
#include <hip/hip_runtime.h>
#include <math.h>

#define NDET 10647
#define NB 4
#define NCLS 80
#define CAP 160   // per-(image,class) bucket capacity; expected ~66±8, 160 ≈ 11 sigma

// numerically-stable sigmoid, mirrors jax.nn.sigmoid's f32 behavior
__device__ __forceinline__ float sigmoidf_ref(float x) {
    if (x >= 0.f) {
        return 1.f / (1.f + expf(-x));
    } else {
        float e = expf(x);
        return e / (1.f + e);
    }
}

// Thread-per-cell decode. For fixed channel j, consecutive cells are
// contiguous in memory -> coalesced wave loads. Class argmax on RAW logits
// (sigmoid monotonic; first-max strict-> tie rule preserved: 4 in-order
// chains over [0,20)/[20,40)/[40,60)/[60,80), merged in index order).
// Chains are processed as 4 SEQUENTIAL chunks of 20 loads so at most ~20
// logit registers are live at once -> no VGPR spill (R7 lesson: the v[80]
// register array spilled to scratch at VGPR_Count=64).
template <int S>
__device__ __forceinline__ void decode_cell(
    const float* __restrict__ feat, int b, int a, int cell, int off, float sx,
    float anchw, float anchh, float* __restrict__ det, float* __restrict__ keep,
    int* __restrict__ counts, float4* __restrict__ bbox,
    float* __restrict__ bconf, int* __restrict__ bidx)
{
    const int SS = S * S;
    const int h = cell / S;
    const int w = cell - h * S;
    const float* p = feat + ((size_t)(b * 255 + a * 85)) * SS + cell;

    float t0 = p[0 * SS];
    float t1 = p[1 * SS];
    float t2 = p[2 * SS];
    float t3 = p[3 * SS];
    float t4 = p[4 * SS];

#define CHAIN20(MV, IV, BASE)                                          \
    {                                                                  \
        float vv[20];                                                  \
        _Pragma("unroll")                                              \
        for (int j = 0; j < 20; ++j)                                   \
            vv[j] = p[(size_t)(5 + (BASE) + j) * SS];                  \
        MV = vv[0]; IV = (BASE);                                       \
        _Pragma("unroll")                                              \
        for (int j = 1; j < 20; ++j)                                   \
            if (vv[j] > MV) { MV = vv[j]; IV = (BASE) + j; }           \
    }

    float m0, m1, m2, m3;
    int i0, i1, i2, i3;
    CHAIN20(m0, i0, 0)
    CHAIN20(m1, i1, 20)
    CHAIN20(m2, i2, 40)
    CHAIN20(m3, i3, 60)
#undef CHAIN20

    float best = m0; int cls = i0;
    if (m1 > best) { best = m1; cls = i1; }
    if (m2 > best) { best = m2; cls = i2; }
    if (m3 > best) { best = m3; cls = i3; }

    float x  = (sigmoidf_ref(t0) + (float)w) * sx;
    float y  = (sigmoidf_ref(t1) + (float)h) * sx;
    float bw = expf(t2) * anchw * sx;
    float bh = expf(t3) * anchh * sx;
    float conf = sigmoidf_ref(t4);

    float b0 = x - bw * 0.5f;
    float b1 = x + bw * 0.5f;
    float b2 = y - bh * 0.5f;
    float b3 = y + bh * 0.5f;

    const int n = off + (w * S + h) * 3 + a;
    // det rows are 6 floats = 24B -> always 8B aligned: three float2 stores
    float2* o = reinterpret_cast<float2*>(det + ((size_t)b * NDET + n) * 6);
    o[0] = make_float2(b0, b1);
    o[1] = make_float2(b2, b3);
    o[2] = make_float2(conf, (float)cls);

    if (conf > 0.5f) {
        int bk = b * NCLS + cls;
        int pos = atomicAdd(&counts[bk], 1);
        if (pos < CAP) {
            int slot = bk * CAP + pos;
            bbox[slot]  = make_float4(b0, b1, b2, b3);
            bconf[slot] = conf;
            bidx[slot]  = n;
        }
    } else {
        keep[(size_t)b * NDET + n] = 0.f;
    }
}

// grid = (15, 3, 4): x = cell-chunk (0-10: S=52, 11-13: S=26, 14: S=13),
// y = anchor, z = image. launch_bounds(...,1) lifts any occupancy-driven
// VGPR cap so nothing spills.
__global__ __launch_bounds__(256, 1) void decode_kernel(
    const float* __restrict__ f0, const float* __restrict__ f1,
    const float* __restrict__ f2, float* __restrict__ det,
    float* __restrict__ keep, int* __restrict__ counts,
    float4* __restrict__ bbox, float* __restrict__ bconf, int* __restrict__ bidx)
{
    const int b = blockIdx.z;
    const int a = blockIdx.y;
    const int cx = blockIdx.x;
    const int tid = threadIdx.x;

    if (cx < 11) {
        int cell = cx * 256 + tid;
        if (cell < 52 * 52) {
            const float aw[3] = {10.f, 16.f, 33.f}, ah[3] = {13.f, 30.f, 23.f};
            decode_cell<52>(f0, b, a, cell, 0, 8.f, aw[a], ah[a],
                            det, keep, counts, bbox, bconf, bidx);
        }
    } else if (cx < 14) {
        int cell = (cx - 11) * 256 + tid;
        if (cell < 26 * 26) {
            const float aw[3] = {30.f, 62.f, 59.f}, ah[3] = {61.f, 45.f, 119.f};
            decode_cell<26>(f1, b, a, cell, 8112, 16.f, aw[a], ah[a],
                            det, keep, counts, bbox, bconf, bidx);
        }
    } else {
        int cell = tid;
        if (cell < 13 * 13) {
            const float aw[3] = {116.f, 156.f, 373.f}, ah[3] = {90.f, 198.f, 326.f};
            decode_cell<13>(f2, b, a, cell, 10140, 32.f, aw[a], ah[a],
                            det, keep, counts, bbox, bconf, bidx);
        }
    }
}

// One block per (image,class) bucket. Bucket staged in LDS; each thread owns
// one entry and does a branch-free scan over the whole bucket (order-invariant
// OR, so atomic fill order cannot change the output).
__global__ __launch_bounds__(192) void nms_kernel(
    const int* __restrict__ counts, const float4* __restrict__ bbox,
    const float* __restrict__ bconf, const int* __restrict__ bidx,
    float* __restrict__ keep)
{
    const int bk = blockIdx.x;          // b*NCLS + cls
    const int b = bk / NCLS;
    int cnt = counts[bk];
    if (cnt > CAP) cnt = CAP;

    __shared__ float4 sb[CAP];
    __shared__ float  sc[CAP];
    __shared__ int    si[CAP];
    const int t = threadIdx.x;
    if (t < cnt) {
        sb[t] = bbox[bk * CAP + t];
        sc[t] = bconf[bk * CAP + t];
        si[t] = bidx[bk * CAP + t];
    }
    __syncthreads();
    if (t >= cnt) return;

    float4 me = sb[t];
    float ci = sc[t];
    // replicate reference exactly: area uses (b2-b0) x (b3-b1)
    float ai = fmaxf(me.z - me.x + 1.f, 0.f) * fmaxf(me.w - me.y + 1.f, 0.f);
    float kv = 0.f;
    for (int j = 0; j < cnt; ++j) {
        float cj = sc[j];
        float4 c = sb[j];
        float xmin = fmaxf(me.x, c.x);
        float ymin = fmaxf(me.y, c.y);
        float xmax = fminf(me.z, c.z);
        float ymax = fminf(me.w, c.w);
        float inter = fmaxf(xmax - xmin + 1.f, 0.f) * fmaxf(ymax - ymin + 1.f, 0.f);
        float aj = fmaxf(c.z - c.x + 1.f, 0.f) * fmaxf(c.w - c.y + 1.f, 0.f);
        float iou = inter / (ai + aj - inter);
        // NaN (0/0) compares false, same as numpy
        if (cj > ci && iou > 0.4f) kv = 1.f;
    }
    keep[(size_t)b * NDET + si[t]] = kv;
}

extern "C" void kernel_launch(void* const* d_in, const int* in_sizes, int n_in,
                              void* d_out, int out_size, void* d_ws, size_t ws_size,
                              hipStream_t stream) {
    const float* f0 = (const float*)d_in[0];
    const float* f1 = (const float*)d_in[1];
    const float* f2 = (const float*)d_in[2];
    float* det  = (float*)d_out;                       // (B, 10647, 6)
    float* keep = det + (size_t)NB * NDET * 6;         // (B, 10647) as 0/1 floats

    // workspace layout
    char* ws = (char*)d_ws;
    int* counts = (int*)ws;                             ws += NB * NCLS * sizeof(int);
    ws = (char*)(((uintptr_t)ws + 15) & ~(uintptr_t)15);
    float4* bbox = (float4*)ws;                         ws += (size_t)NB * NCLS * CAP * sizeof(float4);
    float* bconf = (float*)ws;                          ws += (size_t)NB * NCLS * CAP * sizeof(float);
    int*   bidx  = (int*)ws;

    hipMemsetAsync(counts, 0, NB * NCLS * sizeof(int), stream);

    dim3 gdec(15, 3, NB);
    hipLaunchKernelGGL(decode_kernel, gdec, dim3(256), 0, stream,
                       f0, f1, f2, det, keep, counts, bbox, bconf, bidx);

    hipLaunchKernelGGL(nms_kernel, dim3(NB * NCLS), dim3(192), 0, stream,
                       counts, bbox, bconf, bidx, keep);
}